// Round 8
// baseline (312.882 us; speedup 1.0000x reference)
//
#include <hip/hip_runtime.h>
#include <stdint.h>

#define M_TOT 16384      // B*S = 4*4096
#define K_DIM 2048
#define N_DIM 2048
#define W_ELEMS (N_DIM * K_DIM)   // 4194304

typedef int v4i  __attribute__((ext_vector_type(4)));

// ---------------- async global -> LDS, 16B per lane ----------------
__device__ __forceinline__ void async_load16(const void* gptr, void* lptr) {
    __builtin_amdgcn_global_load_lds(
        (__attribute__((address_space(1))) void*)(uintptr_t)gptr,
        (__attribute__((address_space(3))) void*)(uint32_t)(uintptr_t)lptr,
        16, 0, 0);
}

__device__ __forceinline__ int qclamp(float v, int lo, int hi) {
    int q = (int)rintf(v);
    q = q > hi ? hi : (q < lo ? lo : q);
    return q & 255;
}

// ---------------- K1: per-block weight sum partials ----------------
__global__ __launch_bounds__(256) void wsum_kernel(const float* __restrict__ w,
                                                   double* __restrict__ spart) {
    int tid = blockIdx.x * 256 + threadIdx.x;
    const float4* w4 = (const float4*)w;
    double s = 0.0;
    #pragma unroll
    for (int it = 0; it < 8; it++) {               // 512*256*8 float4 = W_ELEMS/4 exact
        float4 v = w4[tid + it * 131072];
        s += (double)v.x + (double)v.y + (double)v.z + (double)v.w;
    }
    #pragma unroll
    for (int off = 32; off; off >>= 1) s += __shfl_down(s, off);
    __shared__ double ls[4];
    if ((threadIdx.x & 63) == 0) ls[threadIdx.x >> 6] = s;
    __syncthreads();
    if (threadIdx.x == 0) spart[blockIdx.x] = ls[0] + ls[1] + ls[2] + ls[3];
}

// ---------------- K2: per-block sum |w - mean| partials ----------------
__global__ __launch_bounds__(256) void wabs_kernel(const float* __restrict__ w,
                                                   const double* __restrict__ spart,
                                                   double* __restrict__ apart) {
    __shared__ double ls[4];
    double sm = spart[threadIdx.x] + spart[threadIdx.x + 256];
    #pragma unroll
    for (int off = 32; off; off >>= 1) sm += __shfl_down(sm, off);
    if ((threadIdx.x & 63) == 0) ls[threadIdx.x >> 6] = sm;
    __syncthreads();
    double mean = (ls[0] + ls[1] + ls[2] + ls[3]) * (1.0 / (double)W_ELEMS);
    __syncthreads();                                // ls reused below
    int tid = blockIdx.x * 256 + threadIdx.x;
    const float4* w4 = (const float4*)w;
    double s = 0.0;
    #pragma unroll
    for (int it = 0; it < 8; it++) {
        float4 v = w4[tid + it * 131072];
        s += fabs((double)v.x - mean) + fabs((double)v.y - mean) +
             fabs((double)v.z - mean) + fabs((double)v.w - mean);
    }
    #pragma unroll
    for (int off = 32; off; off >>= 1) s += __shfl_down(s, off);
    if ((threadIdx.x & 63) == 0) ls[threadIdx.x >> 6] = s;
    __syncthreads();
    if (threadIdx.x == 0) apart[blockIdx.x] = ls[0] + ls[1] + ls[2] + ls[3];
}

// ---------------- K3: fused x-quant (blocks 0..4095) + w-quant (4096..8191) ----
// wq layout for direct-to-register B loads in the GEMM:
//   byte addr = (o>>5)*65536 + (k>>4)*512 + (o&31)*16 + (k&15)
// so a wave reading 32 consecutive o-rows of one 16B k-chunk is one coalesced 512B
// segment pair -- B never touches LDS in the GEMM.
__global__ __launch_bounds__(256) void quant_kernel(
    const float* __restrict__ x, const float* __restrict__ w,
    const double* __restrict__ spart, const double* __restrict__ apart,
    int8_t* __restrict__ xq, int8_t* __restrict__ wq,
    float* __restrict__ xscale, float* __restrict__ wsf)
{
    const int t = threadIdx.x;
    if (blockIdx.x < 4096) {
        // ---- per-row absmax int8 quant of x: one wave per row ----
        const int row  = (blockIdx.x << 2) | (t >> 6);
        const int lane = t & 63;
        const float4* xr = (const float4*)(x + (size_t)row * K_DIM);
        float4 v[8];
        #pragma unroll
        for (int i = 0; i < 8; i++) v[i] = xr[lane + (i << 6)];
        float m = 0.0f;
        #pragma unroll
        for (int i = 0; i < 8; i++)
            m = fmaxf(m, fmaxf(fmaxf(fabsf(v[i].x), fabsf(v[i].y)),
                               fmaxf(fabsf(v[i].z), fabsf(v[i].w))));
        #pragma unroll
        for (int off = 32; off; off >>= 1) m = fmaxf(m, __shfl_xor(m, off));
        const float scale = fmaxf(m, 1e-5f);
        if (lane == 0) xscale[row] = scale;
        int* outp = (int*)(xq + (size_t)row * K_DIM);
        #pragma unroll
        for (int i = 0; i < 8; i++) {
            int p = qclamp(v[i].x / scale * 127.0f, -128, 127)
                  | (qclamp(v[i].y / scale * 127.0f, -128, 127) << 8)
                  | (qclamp(v[i].z / scale * 127.0f, -128, 127) << 16)
                  | (qclamp(v[i].w / scale * 127.0f, -128, 127) << 24);
            outp[lane + (i << 6)] = p;
        }
    } else {
        // ---- ternary w-quant into the chunked layout ----
        __shared__ double ls0[4], ls1[4];
        double s0 = spart[t] + spart[t + 256];
        double s1 = apart[t] + apart[t + 256];
        #pragma unroll
        for (int off = 32; off; off >>= 1) {
            s0 += __shfl_down(s0, off);
            s1 += __shfl_down(s1, off);
        }
        if ((t & 63) == 0) { ls0[t >> 6] = s0; ls1[t >> 6] = s1; }
        __syncthreads();
        float mean  = (float)((ls0[0] + ls0[1] + ls0[2] + ls0[3]) * (1.0 / (double)W_ELEMS));
        float scale = (float)fmax((ls1[0] + ls1[1] + ls1[2] + ls1[3]) * (1.0 / (double)W_ELEMS), 1e-5);
        int i = (blockIdx.x - 4096) * 256 + t;      // one float4 per thread, exact cover
        float4 v = ((const float4*)w)[i];
        int p = qclamp((v.x - mean) / scale, -1, 1)
              | (qclamp((v.y - mean) / scale, -1, 1) << 8)
              | (qclamp((v.z - mean) / scale, -1, 1) << 16)
              | (qclamp((v.w - mean) / scale, -1, 1) << 24);
        const int o  = i >> 9;                      // 512 float4 per weight row
        const int kw = i & 511;                     // float4 index within the row
        // word index in chunked layout: (o>>5)*16384 + (kw>>2)*128 + (o&31)*4 + (kw&3)
        ((int*)wq)[((o >> 5) << 14) + ((kw >> 2) << 7) + ((o & 31) << 2) + (kw & 3)] = p;
        if (i == 0) wsf[0] = scale * (1.0f / 127.0f);   // dequant factor for gemm
    }
}

// ---------------- int8 GEMM: 256x256 tile, BK=64, 8 waves, A-LDS + B-from-L2 ----
// R1-R7 post-mortem: 5 sync structures all land at 3225 cyc/tile = LDS pipe
// (~1400) + MFMA (~1306) + overhead, serialized -- scheduling never overlapped
// them. So this round SHRINKS the LDS term instead: B is read straight from the
// L2-resident chunked wq (4 MB) into registers (4 coalesced 16B loads per wave
// per tile, issued a full tile ~1300 cyc before use >> 200 cyc L2 latency),
// single-spare double buffer in NAMED regs (bf0/bf1, static indexing).
// A keeps the PROVEN-0-conflict path (R1/R2/R6/R7): 16-row 16x16x64 fragments,
// [256 rows][64B] with chunk-slot swizzle s = c^((r>>1)&3) on the global
// source, 3 LDS buffers (48 KiB total), counted vmcnt(2) (only the newest
// A-DMA pair may stay in flight across the one barrier per tile).
// New LDS term: 64 b128 reads + 16 KB DMA writes ~ 900 cyc/tile.
__global__ __launch_bounds__(512, 2) void gemm_i8_kernel(
    const int8_t* __restrict__ xq, const int8_t* __restrict__ wq,
    const float* __restrict__ xscale, const float* __restrict__ wsf,
    float* __restrict__ out)
{
    __shared__ __align__(16) int8_t lsA[3][16384];   // [buf][row*64 + slot*16]

    const int tid  = threadIdx.x;
    const int lane = tid & 63;
    const int wv   = tid >> 6;

    // bijective XCD swizzle: 512 wgs, 64/XCD; XCD x owns bm in [8x,8x+8), bn fastest
    const int flat = blockIdx.x;
    const int nf   = ((flat & 7) << 6) | (flat >> 3);
    const int bm   = nf >> 3;                        // 0..63
    const int bn   = nf & 7;                         // 0..7

    // A staging: pair covers (row = tid>>2 in 0..127, slot = tid&3) and row+128
    // data chunk stored at slot s of row r is c = s ^ ((r>>1)&3); (r+128) keeps the xor
    const int sChunk = (((tid & 3) ^ ((tid >> 3) & 3)) << 4);
    const int8_t* gAb = xq + (size_t)(bm * 256 + (tid >> 2)) * K_DIM + sChunk;

    #define STAGE_A(NB, T)                                                     \
        do {                                                                   \
            async_load16(gAb + ((size_t)(T) << 6),       lsA[NB] + tid * 16);  \
            async_load16(gAb + ((size_t)(T) << 6) + (size_t)128 * K_DIM,       \
                         lsA[NB] + 8192 + tid * 16);                           \
        } while (0)

    // per-wave fragments (16x16x64: row = lane&15, k-chunk = lane>>4)
    const int wm = (wv >> 2) << 7;                   // 0 / 128
    const int wn = (wv & 3) << 6;                    // 0 / 64 / 128 / 192
    const int fr = lane & 15;
    const int fc = lane >> 4;                        // 16B k-chunk 0..3
    int aoff[8];
    #pragma unroll
    for (int mi = 0; mi < 8; mi++) {
        int ra = wm + mi * 16 + fr;
        aoff[mi] = ra * 64 + ((fc ^ ((ra >> 1) & 3)) << 4);
    }

    // B direct-from-L2 (chunked wq): fragment nj, tile T at
    //   gB + (nj>>1)*65536 + (nj&1)*256 + T*2048
    const int8_t* gB = wq + (((size_t)((bn * 256 + wn) >> 5)) << 16)
                          + (fc << 9) + (fr << 4);
    v4i bf0[4], bf1[4];
    #define LOADB(DST, T)                                                      \
        do {                                                                   \
            const int8_t* p_ = gB + ((size_t)(T) << 11);                       \
            DST[0] = *(const v4i*)(p_);                                        \
            DST[1] = *(const v4i*)(p_ + 256);                                  \
            DST[2] = *(const v4i*)(p_ + 65536);                                \
            DST[3] = *(const v4i*)(p_ + 65536 + 256);                          \
        } while (0)

    v4i acc[8][4] = {};

    #define COMPUTE(CURB, BC)                                                  \
        do {                                                                   \
            v4i af[8];                                                         \
            _Pragma("unroll")                                                  \
            for (int mi_ = 0; mi_ < 8; mi_++)                                  \
                af[mi_] = *(const v4i*)(lsA[CURB] + aoff[mi_]);                \
            __builtin_amdgcn_s_setprio(1);                                     \
            _Pragma("unroll")                                                  \
            for (int mi_ = 0; mi_ < 8; mi_++)                                  \
                _Pragma("unroll")                                              \
                for (int nj_ = 0; nj_ < 4; nj_++)                              \
                    acc[mi_][nj_] = __builtin_amdgcn_mfma_i32_16x16x64_i8(     \
                        af[mi_], BC[nj_], acc[mi_][nj_], 0, 0, 0);             \
            __builtin_amdgcn_s_setprio(0);                                     \
        } while (0)

    // TILE t (t <= 29): prefetch B(t+1)->BN, stage A(t+2), compute A(t)xB(t),
    // vmcnt(2): only the A(t+2) DMA pair may stay in flight across the barrier
    // (A(t+1) issued 1 tile ago > HBM latency; B(t+1) issued this tile > L2 lat).
    #define TILE(T, CURB, STB, BC, BN)                                         \
        do {                                                                   \
            LOADB(BN, (T) + 1);                                                \
            STAGE_A(STB, (T) + 2);                                             \
            COMPUTE(CURB, BC);                                                 \
            asm volatile("s_waitcnt vmcnt(2)" ::: "memory");                   \
            __builtin_amdgcn_s_barrier();                                      \
        } while (0)

    // prologue: A(0)->buf0, B(0)->bf0, A(1)->buf1 in flight
    STAGE_A(0, 0);
    LOADB(bf0, 0);
    STAGE_A(1, 1);
    asm volatile("s_waitcnt vmcnt(2)" ::: "memory");
    __builtin_amdgcn_s_barrier();

    for (int tt = 0; tt < 30; tt += 6) {
        TILE(tt,     0, 2, bf0, bf1);
        TILE(tt + 1, 1, 0, bf1, bf0);
        TILE(tt + 2, 2, 1, bf0, bf1);
        TILE(tt + 3, 0, 2, bf1, bf0);
        TILE(tt + 4, 1, 0, bf0, bf1);
        TILE(tt + 5, 2, 1, bf1, bf0);
    }
    // t = 30: prefetch B(31), nothing left to stage; full drain (all loads old)
    LOADB(bf1, 31);
    COMPUTE(0, bf0);
    asm volatile("s_waitcnt vmcnt(0)" ::: "memory");
    __builtin_amdgcn_s_barrier();
    // t = 31: last tile
    COMPUTE(1, bf1);

    #undef TILE
    #undef COMPUTE
    #undef LOADB
    #undef STAGE_A

    // epilogue: dequant. 16x16 C/D: col = lane&15, row = (lane>>4)*4 + reg
    const float f127 = wsf[0];
    #pragma unroll
    for (int mi = 0; mi < 8; mi++) {
        #pragma unroll
        for (int rg = 0; rg < 4; rg++) {
            const int mg = bm * 256 + wm + mi * 16 + (lane >> 4) * 4 + rg;
            const float fs = f127 * xscale[mg];
            float* orow = out + (size_t)mg * N_DIM + bn * 256 + wn;
            #pragma unroll
            for (int nj = 0; nj < 4; nj++)
                orow[nj * 16 + fr] = fs * (float)acc[mi][nj][rg];
        }
    }
}

extern "C" void kernel_launch(void* const* d_in, const int* in_sizes, int n_in,
                              void* d_out, int out_size, void* d_ws, size_t ws_size,
                              hipStream_t stream) {
    const float* x = (const float*)d_in[0];
    const float* w = (const float*)d_in[1];
    float* out = (float*)d_out;

    char* ws = (char*)d_ws;
    double* spart  = (double*)ws;                    // 4 KB (512 doubles)
    double* apart  = (double*)(ws + 4096);           // 4 KB
    float*  wsf    = (float*)(ws + 8192);            // 4 B
    float*  xscale = (float*)(ws + 12288);           // 64 KB
    int8_t* xq     = (int8_t*)(ws + 12288 + 65536);  // 32 MB
    int8_t* wq     = xq + (size_t)M_TOT * K_DIM;     // 4 MB (chunked layout)

    wsum_kernel <<<512, 256, 0, stream>>>(w, spart);
    wabs_kernel <<<512, 256, 0, stream>>>(w, spart, apart);
    quant_kernel<<<8192, 256, 0, stream>>>(x, w, spart, apart, xq, wq, xscale, wsf);
    gemm_i8_kernel<<<512, 512, 0, stream>>>(xq, wq, xscale, wsf, out);
}